// Round 7
// baseline (158.642 us; speedup 1.0000x reference)
//
#include <hip/hip_runtime.h>
#include <math.h>

// Problem constants
#define B 2
#define N 8192
#define M 8192
#define NPTS (B*N)
#define VD 64
#define VH 128
#define VW 128
#define VVOX (VD*VH*VW)         // 1048576 voxels per batch
#define DHH 512
#define DWW 512
#define DPIX (DHH*DWW)

// Chamfer tiling
#define QT 8
#define SEGS 32
#define TSEG (M/SEGS)           // 256 targets per block

// Workspace layout (float indices). NO atomics, NO device-scope fences.
// 3D erosion is fully fused (register-rolling d-window) -> no WH intermediate.
#define OFF_CHPART 0                        // [2 dirs][32 segs][16384 q] partial mins
#define OFF_PCL    1048576                  // [3 terms][256 blk] cldice partials
#define OFF_PDE    1049344                  // [6 terms][256 blk] depth partials
#define OFF_PCH    1050880                  // [64] chamfer block partial sums

__device__ __forceinline__ float blockSum(float v, volatile float* sm) {
    #pragma unroll
    for (int o = 32; o > 0; o >>= 1) v += __shfl_down(v, o, 64);
    int lane = threadIdx.x & 63, wid = threadIdx.x >> 6;
    __syncthreads();
    if (lane == 0) sm[wid] = v;
    __syncthreads();
    return sm[0] + sm[1] + sm[2] + sm[3];
}

__device__ __forceinline__ float min3f(float a, float b, float c) {
    return fminf(a, fminf(b, c));
}

__device__ __forceinline__ float sumRange(const float* p, int n, volatile float* sm) {
    float s = 0.f;
    for (int t = threadIdx.x; t < n; t += 256) s += p[t];
    return blockSum(s, sm);
}

// (w,h)-erode one plane: 3x3 min in the (w,h) plane for a float4 of w-positions.
// rowU/rowC/rowD are absolute float offsets of the clamped rows in this plane.
__device__ __forceinline__ float4 erodeWH(const float* __restrict__ vol,
                                          int rowU, int rowC, int rowD,
                                          int w4, int q) {
    float4 acc = make_float4(INFINITY, INFINITY, INFINITY, INFINITY);
    int offs[3] = {rowU, rowC, rowD};
    #pragma unroll
    for (int r = 0; r < 3; ++r) {
        const float* rw = vol + offs[r];
        float4 c = *(const float4*)(rw + w4);
        float l  = (q > 0)  ? rw[w4-1] : c.x;   // clamp == SAME(+inf) for min
        float rr = (q < 31) ? rw[w4+4] : c.w;
        acc.x = fminf(acc.x, min3f(l,   c.x, c.y));
        acc.y = fminf(acc.y, min3f(c.x, c.y, c.z));
        acc.z = fminf(acc.z, min3f(c.y, c.z, c.w));
        acc.w = fminf(acc.w, min3f(c.z, c.w, rr));
    }
    return acc;
}

__device__ __forceinline__ float4 min3f4(float4 a, float4 b, float4 c) {
    return make_float4(min3f(a.x,b.x,c.x), min3f(a.y,b.y,c.y),
                       min3f(a.z,b.z,c.z), min3f(a.w,b.w,c.w));
}

// ============================ PHASE 1 =====================================
// blocks [0,512): chamfer partial mins (inline query/target packing)
// blocks [512,768): fused 3D-erode + sigmoid + clDice partial sums
// blocks [768,1024): depth-loss partial sums
__global__ __launch_bounds__(256) void k_phase1(const float* __restrict__ pc,
                                                const float* __restrict__ gp,
                                                const float* __restrict__ pv,
                                                const float* __restrict__ gv,
                                                const float* __restrict__ pd,
                                                const float* __restrict__ gd,
                                                const float* __restrict__ mk,
                                                float* ws) {
    __shared__ float4 smem[TSEG];            // chamfer targets / reduce scratch
    unsigned int bb = blockIdx.x;

    if (bb < 512) {
        // ---------------- chamfer ----------------
        int dir  = bb >> 8;                  // 0: pred->gt, 1: gt->pred
        int rem  = bb & 255;
        int seg  = rem >> 3;
        int qblk = rem & 7;
        const float* Q = dir ? gp : pc;
        const float* T = dir ? pc : gp;
        int qbase = qblk * (256*QT);         // 2048-query chunk, batch-aligned
        int b = qbase >> 13;

        {   // stage + pack 256 targets into LDS
            int t = b*M + seg*TSEG + threadIdx.x;
            float x = T[3*t], y = T[3*t+1], z = T[3*t+2];
            smem[threadIdx.x] = make_float4(x, y, z, x*x + y*y + z*z);
        }
        float nx[QT], ny[QT], nz[QT], q2[QT], dmin[QT];
        #pragma unroll
        for (int k = 0; k < QT; ++k) {
            int i = qbase + k*256 + threadIdx.x;
            float x = Q[3*i], y = Q[3*i+1], z = Q[3*i+2];
            nx[k] = -2.f*x; ny[k] = -2.f*y; nz[k] = -2.f*z;
            q2[k] = x*x + y*y + z*z; dmin[k] = INFINITY;
        }
        __syncthreads();
        #pragma unroll 4
        for (int j = 0; j < TSEG; ++j) {
            float4 tv = smem[j];             // wave-uniform -> LDS broadcast
            #pragma unroll
            for (int k = 0; k < QT; ++k) {
                float d = fmaf(tv.x, nx[k], fmaf(tv.y, ny[k], fmaf(tv.z, nz[k], tv.w)));
                dmin[k] = fminf(dmin[k], d);
            }
        }
        float* part = ws + OFF_CHPART + dir*(SEGS*NPTS) + seg*NPTS + qbase;
        #pragma unroll
        for (int k = 0; k < QT; ++k)
            part[k*256 + threadIdx.x] = dmin[k] + q2[k];

    } else if (bb < 768) {
        // ------- fused 3D erosion + sigmoid + clDice partials -------
        // id -> (batch, d-chunk of 8, h-slab of 8); thread -> (h in slab, w-quad)
        volatile float* sm = (volatile float*)smem;
        int id     = bb - 512;               // [0,256)
        int b      = id >> 7;                // uniform per block
        int rem    = id & 127;
        int dchunk = rem >> 4;               // 0..7 -> d0 = 8*dchunk
        int hslab  = rem & 15;               // 0..15 -> h0 = 8*hslab
        int q      = threadIdx.x & 31;
        int w4     = q * 4;
        int h      = hslab*8 + (threadIdx.x >> 5);
        int d0     = dchunk * 8;

        int base = b*VVOX;
        int rC = h*VW;
        int rU = (h > 0)   ? rC - VW : rC;
        int rD = (h < 127) ? rC + VW : rC;

        // rolling 3-plane window of (w,h)-eroded values
        int pPrev = base + ((d0 > 0) ? (d0-1) : 0) * (VH*VW);
        int pCur  = base + d0 * (VH*VW);
        float4 ppv = erodeWH(pv, pPrev+rU, pPrev+rC, pPrev+rD, w4, q);
        float4 pgv = erodeWH(gv, pPrev+rU, pPrev+rC, pPrev+rD, w4, q);
        float4 cpv = erodeWH(pv, pCur+rU,  pCur+rC,  pCur+rD,  w4, q);
        float4 cgv = erodeWH(gv, pCur+rU,  pCur+rC,  pCur+rD,  w4, q);

        float li = 0.f, lp = 0.f, lg = 0.f;
        #pragma unroll
        for (int dd = 0; dd < 8; ++dd) {
            int d = d0 + dd;
            int pNext = base + ((d < 63) ? (d+1) : 63) * (VH*VW);
            float4 npv = erodeWH(pv, pNext+rU, pNext+rC, pNext+rD, w4, q);
            float4 ngv = erodeWH(gv, pNext+rU, pNext+rC, pNext+rD, w4, q);
            float4 mp = min3f4(ppv, cpv, npv);
            float4 mg = min3f4(pgv, cgv, ngv);
            float4 ps = make_float4(1.f/(1.f+__expf(-mp.x)), 1.f/(1.f+__expf(-mp.y)),
                                    1.f/(1.f+__expf(-mp.z)), 1.f/(1.f+__expf(-mp.w)));
            li += ps.x*mg.x + ps.y*mg.y + ps.z*mg.z + ps.w*mg.w;
            lp += ps.x + ps.y + ps.z + ps.w;
            lg += mg.x + mg.y + mg.z + mg.w;
            ppv = cpv; cpv = npv;
            pgv = cgv; cgv = ngv;
        }
        float a;
        float* part = ws + OFF_PCL;          // [3][256], batch = id>>7
        a = blockSum(li, sm); if (threadIdx.x == 0) part[       id] = a;
        a = blockSum(lp, sm); if (threadIdx.x == 0) part[256  + id] = a;
        a = blockSum(lg, sm); if (threadIdx.x == 0) part[512  + id] = a;

    } else {
        // ---------------- depth partials ----------------
        volatile float* sm = (volatile float*)smem;
        int idx0 = bb - 768;                 // [0,256)
        int b   = idx0 >> 7;
        int blk = idx0 & 127;
        const float* pb = pd + b * DPIX;
        const float* gb = gd + b * DPIX;
        const float* mb = mk + b * DPIX;
        float sg = 0, sg2 = 0, gx = 0, gy = 0, num = 0, den = 0;
        #pragma unroll
        for (int k = 0; k < 8; ++k) {
            int idx = (blk*8 + k)*256 + threadIdx.x;   // [0, DPIX)
            int h = idx >> 9;
            int w = idx & 511;
            float p = pb[idx], g = gb[idx], m = mb[idx];
            float lgv = logf(p + 0.1f) - logf(g + 0.1f);
            sg += lgv; sg2 += lgv * lgv;
            if (h < DHH - 1) {
                float p2 = pb[idx + DWW], g2 = gb[idx + DWW];
                gx += fabsf(fabsf(p - p2) - fabsf(g - g2));
            }
            if (w < DWW - 1) {
                float p2 = pb[idx + 1], g2 = gb[idx + 1];
                gy += fabsf(fabsf(p - p2) - fabsf(g - g2));
            }
            num += fabsf(p - g) * m;
            den += m;
        }
        float a;
        float* part = ws + OFF_PDE;          // [6][256]
        a = blockSum(sg,  sm); if (threadIdx.x == 0) part[       idx0] = a;
        a = blockSum(sg2, sm); if (threadIdx.x == 0) part[256  + idx0] = a;
        a = blockSum(gx,  sm); if (threadIdx.x == 0) part[512  + idx0] = a;
        a = blockSum(gy,  sm); if (threadIdx.x == 0) part[768  + idx0] = a;
        a = blockSum(num, sm); if (threadIdx.x == 0) part[1024 + idx0] = a;
        a = blockSum(den, sm); if (threadIdx.x == 0) part[1280 + idx0] = a;
    }
}

// ============================ PHASE 2 =====================================
// chamfer redmin only: min over 32 segs per query, sum 512 queries per block.
__global__ __launch_bounds__(256) void k_phase2(float* ws) {
    __shared__ float sm[4];
    unsigned int bb = blockIdx.x;            // [0,64)
    int dir = bb >> 5;
    int blk = bb & 31;
    const float* base = ws + OFF_CHPART + dir*(SEGS*NPTS) + blk*512;
    float s = 0.f;
    #pragma unroll
    for (int u = 0; u < 2; ++u) {
        int t = u*256 + threadIdx.x;
        float m = INFINITY;
        #pragma unroll
        for (int sg = 0; sg < SEGS; ++sg) m = fminf(m, base[sg*NPTS + t]);
        s += m;
    }
    float a = blockSum(s, sm);
    if (threadIdx.x == 0) ws[OFF_PCH + bb] = a;
}

// ============================ FINAL =======================================
__global__ __launch_bounds__(256) void k_final(const float* ws, const int* iter,
                                               float* out) {
    __shared__ float sm[4];
    float sch = sumRange(ws + OFF_PCH, 64, sm);
    float i0  = sumRange(ws + OFF_PCL,        128, sm);
    float i1  = sumRange(ws + OFF_PCL + 128,  128, sm);
    float p0  = sumRange(ws + OFF_PCL + 256,  128, sm);
    float p1  = sumRange(ws + OFF_PCL + 384,  128, sm);
    float g0  = sumRange(ws + OFF_PCL + 512,  128, sm);
    float g1  = sumRange(ws + OFF_PCL + 640,  128, sm);
    float sg0 = sumRange(ws + OFF_PDE,        128, sm);
    float sg1 = sumRange(ws + OFF_PDE + 128,  128, sm);
    float s20 = sumRange(ws + OFF_PDE + 256,  128, sm);
    float s21 = sumRange(ws + OFF_PDE + 384,  128, sm);
    float gx  = sumRange(ws + OFF_PDE + 512,  256, sm);
    float gy  = sumRange(ws + OFF_PDE + 768,  256, sm);
    float num = sumRange(ws + OFF_PDE + 1024, 256, sm);
    float den = sumRange(ws + OFF_PDE + 1280, 256, sm);
    if (threadIdx.x != 0) return;

    float chamfer = sch / (float)NPTS;       // (sum_minP + sum_minG)/NPTS
    float dsum = (2.f*i0 + 1e-5f) / (p0 + g0 + 1e-5f)
               + (2.f*i1 + 1e-5f) / (p1 + g1 + 1e-5f);
    float cldice = 1.f - 0.5f * dsum;
    float silog = 0.f;
    {
        float gm = sg0 / (float)DPIX;
        float gv = s20 / (float)DPIX - gm*gm;
        silog += 10.f*0.5f*gv + 10.f*0.5f*gm*gm;
        gm = sg1 / (float)DPIX;
        gv = s21 / (float)DPIX - gm*gm;
        silog += 10.f*0.5f*gv + 10.f*0.5f*gm*gm;
    }
    float grad_l1 = gx / (float)(B*(DHH-1)*DWW) + gy / (float)(B*DHH*(DWW-1));
    float mask_l1 = num / (den + 1e-8f);
    float dloss = silog + grad_l1 + mask_l1;
    int it = iter[0]; if (it < 1) it = 1;
    float gamma1 = 2.f * logf((float)it / 20000.f);
    out[0] = gamma1 * chamfer + 0.5f * cldice + 0.01f * dloss;
}

extern "C" void kernel_launch(void* const* d_in, const int* in_sizes, int n_in,
                              void* d_out, int out_size, void* d_ws, size_t ws_size,
                              hipStream_t stream) {
    const float* pc  = (const float*)d_in[0];
    const float* pv  = (const float*)d_in[1];
    const float* pd  = (const float*)d_in[2];
    const float* gp  = (const float*)d_in[3];
    const float* gvv = (const float*)d_in[4];
    const float* gd  = (const float*)d_in[5];
    const float* mk  = (const float*)d_in[6];
    const int*   it  = (const int*)d_in[7];
    float* ws  = (float*)d_ws;
    float* out = (float*)d_out;

    k_phase1<<<1024, 256, 0, stream>>>(pc, gp, pv, gvv, pd, gd, mk, ws);
    k_phase2<<<64,   256, 0, stream>>>(ws);
    k_final <<<1,    256, 0, stream>>>(ws, it, out);
}

// Round 8
// 138.411 us; speedup vs baseline: 1.1462x; 1.1462x over previous
//
#include <hip/hip_runtime.h>
#include <math.h>

// Problem constants
#define B 2
#define N 8192
#define M 8192
#define NPTS (B*N)
#define VD 64
#define VH 128
#define VW 128
#define VVOX (VD*VH*VW)         // 1048576 voxels per batch
#define DHH 512
#define DWW 512
#define DPIX (DHH*DWW)

// Chamfer tiling
#define QT 8
#define SEGS 32
#define TSEG (M/SEGS)           // 256 targets per block

// Workspace layout (float indices). NO atomics, NO device-scope fences.
// Register-budget isolation: heavy erode lives in phase2, NOT with chamfer
// (branch fusion couples VGPR allocation -> round 7's 184-VGPR chamfer).
#define OFF_CHPART 0                        // [2 dirs][32 segs][16384 q] partial mins
#define OFF_PCL    1048576                  // [3 terms][256 blk] cldice partials
#define OFF_PDE    1049344                  // [6 terms][256 blk] depth partials
#define OFF_PCH    1050880                  // [64] chamfer block partial sums

__device__ __forceinline__ float blockSum(float v, volatile float* sm) {
    #pragma unroll
    for (int o = 32; o > 0; o >>= 1) v += __shfl_down(v, o, 64);
    int lane = threadIdx.x & 63, wid = threadIdx.x >> 6;
    __syncthreads();
    if (lane == 0) sm[wid] = v;
    __syncthreads();
    return sm[0] + sm[1] + sm[2] + sm[3];
}

__device__ __forceinline__ float min3f(float a, float b, float c) {
    return fminf(a, fminf(b, c));
}

__device__ __forceinline__ float sumRange(const float* p, int n, volatile float* sm) {
    float s = 0.f;
    for (int t = threadIdx.x; t < n; t += 256) s += p[t];
    return blockSum(s, sm);
}

// (w,h)-erode one plane: 3x3 min in the (w,h) plane for a float4 of w-positions.
__device__ __forceinline__ float4 erodeWH(const float* __restrict__ vol,
                                          int rowU, int rowC, int rowD,
                                          int w4, int q) {
    float4 acc = make_float4(INFINITY, INFINITY, INFINITY, INFINITY);
    int offs[3] = {rowU, rowC, rowD};
    #pragma unroll
    for (int r = 0; r < 3; ++r) {
        const float* rw = vol + offs[r];
        float4 c = *(const float4*)(rw + w4);
        float l  = (q > 0)  ? rw[w4-1] : c.x;   // clamp == SAME(+inf) for min
        float rr = (q < 31) ? rw[w4+4] : c.w;
        acc.x = fminf(acc.x, min3f(l,   c.x, c.y));
        acc.y = fminf(acc.y, min3f(c.x, c.y, c.z));
        acc.z = fminf(acc.z, min3f(c.y, c.z, c.w));
        acc.w = fminf(acc.w, min3f(c.z, c.w, rr));
    }
    return acc;
}

__device__ __forceinline__ float4 min3f4(float4 a, float4 b, float4 c) {
    return make_float4(min3f(a.x,b.x,c.x), min3f(a.y,b.y,c.y),
                       min3f(a.z,b.z,c.z), min3f(a.w,b.w,c.w));
}

// ============================ PHASE 1 =====================================
// blocks [0,512): chamfer partial mins; blocks [512,768): depth partials.
// Both branches are register-lean -> high occupancy for chamfer latency hiding.
__global__ __launch_bounds__(256) void k_phase1(const float* __restrict__ pc,
                                                const float* __restrict__ gp,
                                                const float* __restrict__ pd,
                                                const float* __restrict__ gd,
                                                const float* __restrict__ mk,
                                                float* ws) {
    __shared__ float4 smem[TSEG];            // chamfer targets / reduce scratch
    unsigned int bb = blockIdx.x;

    if (bb < 512) {
        // ---------------- chamfer ----------------
        int dir  = bb >> 8;                  // 0: pred->gt, 1: gt->pred
        int rem  = bb & 255;
        int seg  = rem >> 3;
        int qblk = rem & 7;
        const float* Q = dir ? gp : pc;
        const float* T = dir ? pc : gp;
        int qbase = qblk * (256*QT);         // 2048-query chunk, batch-aligned
        int b = qbase >> 13;

        {   // stage + pack 256 targets into LDS
            int t = b*M + seg*TSEG + threadIdx.x;
            float x = T[3*t], y = T[3*t+1], z = T[3*t+2];
            smem[threadIdx.x] = make_float4(x, y, z, x*x + y*y + z*z);
        }
        float nx[QT], ny[QT], nz[QT], q2[QT], dmin[QT];
        #pragma unroll
        for (int k = 0; k < QT; ++k) {
            int i = qbase + k*256 + threadIdx.x;
            float x = Q[3*i], y = Q[3*i+1], z = Q[3*i+2];
            nx[k] = -2.f*x; ny[k] = -2.f*y; nz[k] = -2.f*z;
            q2[k] = x*x + y*y + z*z; dmin[k] = INFINITY;
        }
        __syncthreads();
        #pragma unroll 4
        for (int j = 0; j < TSEG; ++j) {
            float4 tv = smem[j];             // wave-uniform -> LDS broadcast
            #pragma unroll
            for (int k = 0; k < QT; ++k) {
                float d = fmaf(tv.x, nx[k], fmaf(tv.y, ny[k], fmaf(tv.z, nz[k], tv.w)));
                dmin[k] = fminf(dmin[k], d);
            }
        }
        float* part = ws + OFF_CHPART + dir*(SEGS*NPTS) + seg*NPTS + qbase;
        #pragma unroll
        for (int k = 0; k < QT; ++k)
            part[k*256 + threadIdx.x] = dmin[k] + q2[k];

    } else {
        // ---------------- depth partials ----------------
        volatile float* sm = (volatile float*)smem;
        int idx0 = bb - 512;                 // [0,256)
        int b   = idx0 >> 7;
        int blk = idx0 & 127;
        const float* pb = pd + b * DPIX;
        const float* gb = gd + b * DPIX;
        const float* mb = mk + b * DPIX;
        float sg = 0, sg2 = 0, gx = 0, gy = 0, num = 0, den = 0;
        #pragma unroll
        for (int k = 0; k < 8; ++k) {
            int idx = (blk*8 + k)*256 + threadIdx.x;   // [0, DPIX)
            int h = idx >> 9;
            int w = idx & 511;
            float p = pb[idx], g = gb[idx], m = mb[idx];
            float lgv = logf(p + 0.1f) - logf(g + 0.1f);
            sg += lgv; sg2 += lgv * lgv;
            if (h < DHH - 1) {
                float p2 = pb[idx + DWW], g2 = gb[idx + DWW];
                gx += fabsf(fabsf(p - p2) - fabsf(g - g2));
            }
            if (w < DWW - 1) {
                float p2 = pb[idx + 1], g2 = gb[idx + 1];
                gy += fabsf(fabsf(p - p2) - fabsf(g - g2));
            }
            num += fabsf(p - g) * m;
            den += m;
        }
        float a;
        float* part = ws + OFF_PDE;          // [6][256]
        a = blockSum(sg,  sm); if (threadIdx.x == 0) part[       idx0] = a;
        a = blockSum(sg2, sm); if (threadIdx.x == 0) part[256  + idx0] = a;
        a = blockSum(gx,  sm); if (threadIdx.x == 0) part[512  + idx0] = a;
        a = blockSum(gy,  sm); if (threadIdx.x == 0) part[768  + idx0] = a;
        a = blockSum(num, sm); if (threadIdx.x == 0) part[1024 + idx0] = a;
        a = blockSum(den, sm); if (threadIdx.x == 0) part[1280 + idx0] = a;
    }
}

// ============================ PHASE 2 =====================================
// blocks [0,64): chamfer redmin; blocks [64,320): fused 3D erode + clDice.
// Heavy-register erode only throttles itself here (small, L2-resident work).
__global__ __launch_bounds__(256) void k_phase2(const float* __restrict__ pv,
                                                const float* __restrict__ gv,
                                                float* ws) {
    __shared__ float sm[4];
    unsigned int bb = blockIdx.x;

    if (bb < 64) {
        // ---------------- chamfer redmin ----------------
        int dir = bb >> 5;
        int blk = bb & 31;
        const float* base = ws + OFF_CHPART + dir*(SEGS*NPTS) + blk*512;
        float s = 0.f;
        #pragma unroll
        for (int u = 0; u < 2; ++u) {
            int t = u*256 + threadIdx.x;
            float m = INFINITY;
            #pragma unroll
            for (int sg = 0; sg < SEGS; ++sg) m = fminf(m, base[sg*NPTS + t]);
            s += m;
        }
        float a = blockSum(s, sm);
        if (threadIdx.x == 0) ws[OFF_PCH + bb] = a;
    } else {
        // ------- fused 3D erosion + sigmoid + clDice partials -------
        int id     = bb - 64;                // [0,256)
        int b      = id >> 7;                // uniform per block
        int rem    = id & 127;
        int dchunk = rem >> 4;               // 0..7 -> d0 = 8*dchunk
        int hslab  = rem & 15;               // 0..15 -> h0 = 8*hslab
        int q      = threadIdx.x & 31;
        int w4     = q * 4;
        int h      = hslab*8 + (threadIdx.x >> 5);
        int d0     = dchunk * 8;

        int base = b*VVOX;
        int rC = h*VW;
        int rU = (h > 0)   ? rC - VW : rC;
        int rD = (h < 127) ? rC + VW : rC;

        // rolling 3-plane window of (w,h)-eroded values
        int pPrev = base + ((d0 > 0) ? (d0-1) : 0) * (VH*VW);
        int pCur  = base + d0 * (VH*VW);
        float4 ppv = erodeWH(pv, pPrev+rU, pPrev+rC, pPrev+rD, w4, q);
        float4 pgv = erodeWH(gv, pPrev+rU, pPrev+rC, pPrev+rD, w4, q);
        float4 cpv = erodeWH(pv, pCur+rU,  pCur+rC,  pCur+rD,  w4, q);
        float4 cgv = erodeWH(gv, pCur+rU,  pCur+rC,  pCur+rD,  w4, q);

        float li = 0.f, lp = 0.f, lg = 0.f;
        #pragma unroll
        for (int dd = 0; dd < 8; ++dd) {
            int d = d0 + dd;
            int pNext = base + ((d < 63) ? (d+1) : 63) * (VH*VW);
            float4 npv = erodeWH(pv, pNext+rU, pNext+rC, pNext+rD, w4, q);
            float4 ngv = erodeWH(gv, pNext+rU, pNext+rC, pNext+rD, w4, q);
            float4 mp = min3f4(ppv, cpv, npv);
            float4 mg = min3f4(pgv, cgv, ngv);
            float4 ps = make_float4(1.f/(1.f+__expf(-mp.x)), 1.f/(1.f+__expf(-mp.y)),
                                    1.f/(1.f+__expf(-mp.z)), 1.f/(1.f+__expf(-mp.w)));
            li += ps.x*mg.x + ps.y*mg.y + ps.z*mg.z + ps.w*mg.w;
            lp += ps.x + ps.y + ps.z + ps.w;
            lg += mg.x + mg.y + mg.z + mg.w;
            ppv = cpv; cpv = npv;
            pgv = cgv; cgv = ngv;
        }
        float a;
        float* part = ws + OFF_PCL;          // [3][256]
        a = blockSum(li, sm); if (threadIdx.x == 0) part[       id] = a;
        a = blockSum(lp, sm); if (threadIdx.x == 0) part[256  + id] = a;
        a = blockSum(lg, sm); if (threadIdx.x == 0) part[512  + id] = a;
    }
}

// ============================ FINAL =======================================
__global__ __launch_bounds__(256) void k_final(const float* ws, const int* iter,
                                               float* out) {
    __shared__ float sm[4];
    float sch = sumRange(ws + OFF_PCH, 64, sm);
    float i0  = sumRange(ws + OFF_PCL,        128, sm);
    float i1  = sumRange(ws + OFF_PCL + 128,  128, sm);
    float p0  = sumRange(ws + OFF_PCL + 256,  128, sm);
    float p1  = sumRange(ws + OFF_PCL + 384,  128, sm);
    float g0  = sumRange(ws + OFF_PCL + 512,  128, sm);
    float g1  = sumRange(ws + OFF_PCL + 640,  128, sm);
    float sg0 = sumRange(ws + OFF_PDE,        128, sm);
    float sg1 = sumRange(ws + OFF_PDE + 128,  128, sm);
    float s20 = sumRange(ws + OFF_PDE + 256,  128, sm);
    float s21 = sumRange(ws + OFF_PDE + 384,  128, sm);
    float gx  = sumRange(ws + OFF_PDE + 512,  256, sm);
    float gy  = sumRange(ws + OFF_PDE + 768,  256, sm);
    float num = sumRange(ws + OFF_PDE + 1024, 256, sm);
    float den = sumRange(ws + OFF_PDE + 1280, 256, sm);
    if (threadIdx.x != 0) return;

    float chamfer = sch / (float)NPTS;       // (sum_minP + sum_minG)/NPTS
    float dsum = (2.f*i0 + 1e-5f) / (p0 + g0 + 1e-5f)
               + (2.f*i1 + 1e-5f) / (p1 + g1 + 1e-5f);
    float cldice = 1.f - 0.5f * dsum;
    float silog = 0.f;
    {
        float gm = sg0 / (float)DPIX;
        float gv = s20 / (float)DPIX - gm*gm;
        silog += 10.f*0.5f*gv + 10.f*0.5f*gm*gm;
        gm = sg1 / (float)DPIX;
        gv = s21 / (float)DPIX - gm*gm;
        silog += 10.f*0.5f*gv + 10.f*0.5f*gm*gm;
    }
    float grad_l1 = gx / (float)(B*(DHH-1)*DWW) + gy / (float)(B*DHH*(DWW-1));
    float mask_l1 = num / (den + 1e-8f);
    float dloss = silog + grad_l1 + mask_l1;
    int it = iter[0]; if (it < 1) it = 1;
    float gamma1 = 2.f * logf((float)it / 20000.f);
    out[0] = gamma1 * chamfer + 0.5f * cldice + 0.01f * dloss;
}

extern "C" void kernel_launch(void* const* d_in, const int* in_sizes, int n_in,
                              void* d_out, int out_size, void* d_ws, size_t ws_size,
                              hipStream_t stream) {
    const float* pc  = (const float*)d_in[0];
    const float* pv  = (const float*)d_in[1];
    const float* pd  = (const float*)d_in[2];
    const float* gp  = (const float*)d_in[3];
    const float* gvv = (const float*)d_in[4];
    const float* gd  = (const float*)d_in[5];
    const float* mk  = (const float*)d_in[6];
    const int*   it  = (const int*)d_in[7];
    float* ws  = (float*)d_ws;
    float* out = (float*)d_out;

    k_phase1<<<768, 256, 0, stream>>>(pc, gp, pd, gd, mk, ws);
    k_phase2<<<320, 256, 0, stream>>>(pv, gvv, ws);
    k_final <<<1,   256, 0, stream>>>(ws, it, out);
}